// Round 8
// baseline (425.437 us; speedup 1.0000x reference)
//
#include <hip/hip_runtime.h>
#include <hip/hip_bf16.h>

// CrossAttention: B=4, Tv=8192, Tt=77, C=1024, H=16, D=64
// Round 7: (1) video fp32->bf16 fused into q-GEMM A-staging (ds_write path, same swizzle);
//          (2) attn v4: 512-thread blocks (256 rows), vectorized V^T staging.

typedef __attribute__((ext_vector_type(8))) short bf16x8;
typedef __attribute__((ext_vector_type(4))) float f32x4;
typedef __attribute__((ext_vector_type(8))) unsigned short u16x8;
typedef __attribute__((ext_vector_type(4))) unsigned short u16x4;

typedef const __attribute__((address_space(1))) void gv_t;
typedef __attribute__((address_space(3))) void lv_t;

static __device__ __forceinline__ unsigned short f2bf(float f) {
    union { float f; unsigned u; } v; v.f = f;
    unsigned r = v.u + 0x7FFFu + ((v.u >> 16) & 1u);  // RNE
    return (unsigned short)(r >> 16);
}

constexpr int Bn = 4, TVn = 8192, TTn = 77, Cn = 1024, Hn = 16;

// ---------------- fp32 -> bf16 convert, 8 elems/thread (weights only now) ----------------
__global__ void k_cvt8(const float* __restrict__ in, unsigned short* __restrict__ out, int n8) {
    int i = blockIdx.x * 256 + threadIdx.x;
    if (i >= n8) return;
    const float4* p = reinterpret_cast<const float4*>(in) + (size_t)i * 2;
    float4 a = p[0], b = p[1];
    u16x8 o = { f2bf(a.x), f2bf(a.y), f2bf(a.z), f2bf(a.w),
                f2bf(b.x), f2bf(b.y), f2bf(b.z), f2bf(b.w) };
    *reinterpret_cast<u16x8*>(out + (size_t)i * 8) = o;
}

// ---------------- q-GEMM with fused A-convert: video fp32 @ Wq bf16^T -> q bf16 ----------------
// A staged via reg-convert + ds_write_b128 (write pos = bseg, source seg = bseg^swz);
// B via global_load_lds with pre-swizzled source. Read side identical to proven kernel.
__global__ __launch_bounds__(256)
void k_gemm_qf(const float* __restrict__ A, const unsigned short* __restrict__ Wb,
               unsigned short* __restrict__ outp) {
    __shared__ unsigned short As[128 * 32];
    __shared__ unsigned short Bs[128 * 32];
    const int tid = threadIdx.x, lane = tid & 63, wv = tid >> 6;
    const int orig = blockIdx.x;
    const int work = (orig & 7) * 256 + (orig >> 3);   // bijective XCD swizzle
    const int m0 = (work >> 3) * 128, n0 = (work & 7) * 128;
    const int wr = (wv >> 1) * 64, wc = (wv & 1) * 64;
    const int lr = lane & 15, lg = lane >> 4;
    const int brow = lane >> 2, bseg = lane & 3;
    f32x4 acc[4][4] = {};
    for (int kk = 0; kk < 1024; kk += 32) {
        #pragma unroll
        for (int j = 0; j < 2; ++j) {
            int chunk = wv * 2 + j;
            int trow = chunk * 16 + brow;
            int sseg = bseg ^ ((trow >> 1) & 3);     // pre-swizzled source segment
            const unsigned short* gb = Wb + (size_t)(n0 + trow) * 1024 + kk + sseg * 8;
            __builtin_amdgcn_global_load_lds((gv_t*)gb, (lv_t*)&Bs[chunk * 512], 16, 0, 0);
            const float4* ga = reinterpret_cast<const float4*>(
                A + (size_t)(m0 + trow) * 1024 + kk + sseg * 8);
            float4 a0 = ga[0], a1 = ga[1];
            uint4 w;
            w.x = (unsigned)f2bf(a0.x) | ((unsigned)f2bf(a0.y) << 16);
            w.y = (unsigned)f2bf(a0.z) | ((unsigned)f2bf(a0.w) << 16);
            w.z = (unsigned)f2bf(a1.x) | ((unsigned)f2bf(a1.y) << 16);
            w.w = (unsigned)f2bf(a1.z) | ((unsigned)f2bf(a1.w) << 16);
            *reinterpret_cast<uint4*>(&As[trow * 32 + bseg * 8]) = w;   // linear position
        }
        __syncthreads();
        bf16x8 af[4], bfv[4];
        #pragma unroll
        for (int m = 0; m < 4; ++m) {
            int R = wr + m * 16 + lr;
            int seg = lg ^ ((R >> 1) & 3);
            af[m] = *reinterpret_cast<const bf16x8*>(&As[R * 32 + seg * 8]);
        }
        #pragma unroll
        for (int n = 0; n < 4; ++n) {
            int R = wc + n * 16 + lr;
            int seg = lg ^ ((R >> 1) & 3);
            bfv[n] = *reinterpret_cast<const bf16x8*>(&Bs[R * 32 + seg * 8]);
        }
        #pragma unroll
        for (int m = 0; m < 4; ++m)
            #pragma unroll
            for (int n = 0; n < 4; ++n)
                acc[m][n] = __builtin_amdgcn_mfma_f32_16x16x32_bf16(af[m], bfv[n], acc[m][n], 0, 0, 0);
        __syncthreads();
    }
    #pragma unroll
    for (int m = 0; m < 4; ++m)
        #pragma unroll
        for (int n = 0; n < 4; ++n)
            #pragma unroll
            for (int r = 0; r < 4; ++r) {
                unsigned short bv = f2bf(acc[m][n][r]);
                unsigned ov = __shfl_xor((unsigned)bv, 1);
                if (!(lane & 1)) {
                    int grow = m0 + wr + m * 16 + lg * 4 + r;
                    int gcol = n0 + wc + n * 16 + lr;
                    *reinterpret_cast<unsigned*>(outp + (size_t)grow * 1024 + gcol) =
                        (unsigned)bv | (ov << 16);
                }
            }
}

// ---------------- unified bf16 GEMM (o-projection): proven round-2 kernel ----------------
template<int OUT_BF16>
__global__ __launch_bounds__(256)
void k_gemm_bb(const unsigned short* __restrict__ A, const unsigned short* __restrict__ Wb,
               void* __restrict__ outp) {
    __shared__ unsigned short As[128 * 32];
    __shared__ unsigned short Bs[128 * 32];
    const int tid = threadIdx.x, lane = tid & 63, wv = tid >> 6;
    const int orig = blockIdx.x;
    const int work = (orig & 7) * 256 + (orig >> 3);
    const int m0 = (work >> 3) * 128, n0 = (work & 7) * 128;
    const int wr = (wv >> 1) * 64, wc = (wv & 1) * 64;
    const int lr = lane & 15, lg = lane >> 4;
    const int brow = lane >> 2, bseg = lane & 3;
    f32x4 acc[4][4] = {};
    for (int kk = 0; kk < 1024; kk += 32) {
        #pragma unroll
        for (int j = 0; j < 2; ++j) {
            int chunk = wv * 2 + j;
            int trow = chunk * 16 + brow;
            int sseg = bseg ^ ((trow >> 1) & 3);
            const unsigned short* ga = A + (size_t)(m0 + trow) * 1024 + kk + sseg * 8;
            __builtin_amdgcn_global_load_lds((gv_t*)ga, (lv_t*)&As[chunk * 512], 16, 0, 0);
            const unsigned short* gb = Wb + (size_t)(n0 + trow) * 1024 + kk + sseg * 8;
            __builtin_amdgcn_global_load_lds((gv_t*)gb, (lv_t*)&Bs[chunk * 512], 16, 0, 0);
        }
        __syncthreads();
        bf16x8 af[4], bfv[4];
        #pragma unroll
        for (int m = 0; m < 4; ++m) {
            int R = wr + m * 16 + lr;
            int seg = lg ^ ((R >> 1) & 3);
            af[m] = *reinterpret_cast<const bf16x8*>(&As[R * 32 + seg * 8]);
        }
        #pragma unroll
        for (int n = 0; n < 4; ++n) {
            int R = wc + n * 16 + lr;
            int seg = lg ^ ((R >> 1) & 3);
            bfv[n] = *reinterpret_cast<const bf16x8*>(&Bs[R * 32 + seg * 8]);
        }
        #pragma unroll
        for (int m = 0; m < 4; ++m)
            #pragma unroll
            for (int n = 0; n < 4; ++n)
                acc[m][n] = __builtin_amdgcn_mfma_f32_16x16x32_bf16(af[m], bfv[n], acc[m][n], 0, 0, 0);
        __syncthreads();
    }
    #pragma unroll
    for (int m = 0; m < 4; ++m)
        #pragma unroll
        for (int n = 0; n < 4; ++n)
            #pragma unroll
            for (int r = 0; r < 4; ++r) {
                int grow = m0 + wr + m * 16 + lg * 4 + r;
                int gcol = n0 + wc + n * 16 + lr;
                if (OUT_BF16) {
                    unsigned short bv = f2bf(acc[m][n][r]);
                    unsigned ov = __shfl_xor((unsigned)bv, 1);
                    if (!(lane & 1)) {
                        unsigned short* out = (unsigned short*)outp;
                        *reinterpret_cast<unsigned*>(out + (size_t)grow * 1024 + gcol) =
                            (unsigned)bv | (ov << 16);
                    }
                } else {
                    float v = acc[m][n][r];
                    float o = __shfl_xor(v, 1);
                    if (!(lane & 1)) {
                        float* out = (float*)outp;
                        float2 pv; pv.x = v; pv.y = o;
                        *reinterpret_cast<float2*>(out + (size_t)grow * 1024 + gcol) = pv;
                    }
                }
            }
}

// ---------------- K/V projection: A fp32 [M][1024] @ W fp32 [1024][1024]^T -> bf16 ----------------
__global__ __launch_bounds__(256)
void k_gemm_kv(const float* __restrict__ A, const float* __restrict__ W0,
               const float* __restrict__ W1, unsigned short* __restrict__ o0,
               unsigned short* __restrict__ o1, int M) {
    const float* W = blockIdx.z ? W1 : W0;
    unsigned short* out = blockIdx.z ? o1 : o0;
    __shared__ unsigned short As[128 * 32];
    __shared__ unsigned short Bs[128 * 32];
    const int tid = threadIdx.x, lane = tid & 63, wv = tid >> 6;
    const int m0 = blockIdx.x * 128, n0 = blockIdx.y * 128;
    const int wr = (wv >> 1) * 64, wc = (wv & 1) * 64;
    const int lr = lane & 15, lk = (lane >> 4) * 8, lg = lane >> 4;
    f32x4 acc[4][4] = {};
    for (int kk = 0; kk < 1024; kk += 32) {
        #pragma unroll
        for (int it = 0; it < 4; ++it) {
            int li = it * 256 + tid;
            int row = li >> 3, c4 = (li & 7) * 4;
            int gr = m0 + row;
            float4 v = make_float4(0.f, 0.f, 0.f, 0.f);
            if (gr < M) v = *reinterpret_cast<const float4*>(A + (size_t)gr * 1024 + kk + c4);
            u16x4 o = { f2bf(v.x), f2bf(v.y), f2bf(v.z), f2bf(v.w) };
            *reinterpret_cast<u16x4*>(&As[row * 32 + c4]) = o;
        }
        #pragma unroll
        for (int it = 0; it < 4; ++it) {
            int li = it * 256 + tid;
            int row = li >> 3, c4 = (li & 7) * 4;
            float4 v = *reinterpret_cast<const float4*>(W + (size_t)(n0 + row) * 1024 + kk + c4);
            u16x4 o = { f2bf(v.x), f2bf(v.y), f2bf(v.z), f2bf(v.w) };
            *reinterpret_cast<u16x4*>(&Bs[row * 32 + c4]) = o;
        }
        __syncthreads();
        bf16x8 af[4], bfv[4];
        #pragma unroll
        for (int m = 0; m < 4; ++m)
            af[m] = *reinterpret_cast<const bf16x8*>(&As[(wr + m * 16 + lr) * 32 + lk]);
        #pragma unroll
        for (int n = 0; n < 4; ++n)
            bfv[n] = *reinterpret_cast<const bf16x8*>(&Bs[(wc + n * 16 + lr) * 32 + lk]);
        #pragma unroll
        for (int m = 0; m < 4; ++m)
            #pragma unroll
            for (int n = 0; n < 4; ++n)
                acc[m][n] = __builtin_amdgcn_mfma_f32_16x16x32_bf16(af[m], bfv[n], acc[m][n], 0, 0, 0);
        __syncthreads();
    }
    #pragma unroll
    for (int m = 0; m < 4; ++m)
        #pragma unroll
        for (int n = 0; n < 4; ++n)
            #pragma unroll
            for (int r = 0; r < 4; ++r) {
                int grow = m0 + wr + m * 16 + lg * 4 + r;
                if (grow < M) {
                    int gcol = n0 + wc + n * 16 + lr;
                    out[(size_t)grow * 1024 + gcol] = f2bf(acc[m][n][r]);
                }
            }
}

// ---------------- attention v4: 256 rows x 1 head per 512-thread block ----------------
// Same verified v3 math per wave (swapped QK^T, in-register P, bpermute redistribution);
// V^T staged once per 256 rows with vectorized u16x8 loads; one barrier.
__global__ __launch_bounds__(512)
void k_attn4(unsigned short* __restrict__ q,        // [32768][1024] bf16, attn written in-place
             const unsigned short* __restrict__ kb, // [308][1024]
             const unsigned short* __restrict__ vb) {
    constexpr int VP = 104;
    __shared__ unsigned short vt_s[64 * VP];         // 13312 B
    const int tid = threadIdx.x, lane = tid & 63, wv = tid >> 6;   // wv 0..7
    const int m0 = blockIdx.x * 256;
    const int h = blockIdx.y, b = blockIdx.z;
    const size_t qbase = ((size_t)b * TVn + m0) * Cn + h * 64;
    const size_t kvbase = (size_t)b * TTn * Cn + h * 64;
    const int lr = lane & 15, lg = lane >> 4;

    // stage V^T: vectorized 16B loads (80 rows x 8 segs = 640 tasks), scatter writes
    for (int li = tid; li < 640; li += 512) {
        int t = li >> 3, sg = li & 7;
        u16x8 v = {0, 0, 0, 0, 0, 0, 0, 0};
        if (t < 77) v = *reinterpret_cast<const u16x8*>(vb + kvbase + (size_t)t * Cn + sg * 8);
        #pragma unroll
        for (int i = 0; i < 8; ++i) vt_s[(sg * 8 + i) * VP + t] = v[i];
    }
    for (int li = tid; li < 1024; li += 512) {       // zero cols 80..95
        int d = li >> 4, t = 80 + (li & 15);
        vt_s[d * VP + t] = 0;
    }

    // QK^T, swapped operands -> P^T layout
    f32x4 sc[2][5] = {};
    #pragma unroll
    for (int ks = 0; ks < 2; ++ks) {
        bf16x8 qa[2], kf[5];
        #pragma unroll
        for (int mf = 0; mf < 2; ++mf)
            qa[mf] = *reinterpret_cast<const bf16x8*>(
                q + qbase + (size_t)(wv * 32 + mf * 16 + lr) * Cn + ks * 32 + lg * 8);
        #pragma unroll
        for (int nf = 0; nf < 5; ++nf) {
            int t = nf * 16 + lr; if (t > 76) t = 76;
            kf[nf] = *reinterpret_cast<const bf16x8*>(
                kb + kvbase + (size_t)t * Cn + ks * 32 + lg * 8);
        }
        #pragma unroll
        for (int mf = 0; mf < 2; ++mf)
            #pragma unroll
            for (int nf = 0; nf < 5; ++nf)
                sc[mf][nf] = __builtin_amdgcn_mfma_f32_16x16x32_bf16(kf[nf], qa[mf], sc[mf][nf], 0, 0, 0);
    }

    // softmax per mf over lane's k = 16nf+4lg+r (mask k>=77)
    unsigned pk[2][6][2];
    constexpr float CEXP = 0.125f * 1.44269504088896340736f;
    #pragma unroll
    for (int mf = 0; mf < 2; ++mf) {
        float mx = -1e30f;
        #pragma unroll
        for (int nf = 0; nf < 5; ++nf)
            #pragma unroll
            for (int r = 0; r < 4; ++r)
                if (!(nf == 4 && r >= 1)) mx = fmaxf(mx, sc[mf][nf][r]);
                else if (lg != 3)         mx = fmaxf(mx, sc[mf][nf][r]);
        mx = fmaxf(mx, __shfl_xor(mx, 16));
        mx = fmaxf(mx, __shfl_xor(mx, 32));
        float p[5][4];
        float sum = 0.f;
        #pragma unroll
        for (int nf = 0; nf < 5; ++nf)
            #pragma unroll
            for (int r = 0; r < 4; ++r) {
                bool valid = !(nf == 4 && lg == 3 && r >= 1);
                float pv = valid ? exp2f((sc[mf][nf][r] - mx) * CEXP) : 0.f;
                p[nf][r] = pv;
                sum += pv;
            }
        sum += __shfl_xor(sum, 16);
        sum += __shfl_xor(sum, 32);
        float inv = 1.f / sum;
        #pragma unroll
        for (int nf = 0; nf < 5; ++nf) {
            pk[mf][nf][0] = (unsigned)f2bf(p[nf][0] * inv) | ((unsigned)f2bf(p[nf][1] * inv) << 16);
            pk[mf][nf][1] = (unsigned)f2bf(p[nf][2] * inv) | ((unsigned)f2bf(p[nf][3] * inv) << 16);
        }
        pk[mf][5][0] = 0; pk[mf][5][1] = 0;
    }

    __syncthreads();  // vt_s staging visible

    // PV with in-register P redistribution
    f32x4 ovv[2][4] = {};
    const int sel = lg >> 1;
    const int srcA = ((lg & 1) * 2) * 16 + lr;
    const int srcB = ((lg & 1) * 2 + 1) * 16 + lr;
    #pragma unroll
    for (int ks = 0; ks < 3; ++ks) {
        bf16x8 vf[4];
        #pragma unroll
        for (int nf = 0; nf < 4; ++nf)
            vf[nf] = *reinterpret_cast<const bf16x8*>(
                &vt_s[(nf * 16 + lr) * VP + ks * 32 + lg * 8]);
        #pragma unroll
        for (int mf = 0; mf < 2; ++mf) {
            unsigned w0l = __shfl(pk[mf][ks * 2 + 0][0], srcA);
            unsigned w0h = __shfl(pk[mf][ks * 2 + 1][0], srcA);
            unsigned w1l = __shfl(pk[mf][ks * 2 + 0][1], srcA);
            unsigned w1h = __shfl(pk[mf][ks * 2 + 1][1], srcA);
            unsigned w2l = __shfl(pk[mf][ks * 2 + 0][0], srcB);
            unsigned w2h = __shfl(pk[mf][ks * 2 + 1][0], srcB);
            unsigned w3l = __shfl(pk[mf][ks * 2 + 0][1], srcB);
            unsigned w3h = __shfl(pk[mf][ks * 2 + 1][1], srcB);
            union { uint4 u; bf16x8 v; } pa;
            pa.u.x = sel ? w0h : w0l;
            pa.u.y = sel ? w1h : w1l;
            pa.u.z = sel ? w2h : w2l;
            pa.u.w = sel ? w3h : w3l;
            #pragma unroll
            for (int nf = 0; nf < 4; ++nf)
                ovv[mf][nf] = __builtin_amdgcn_mfma_f32_16x16x32_bf16(pa.v, vf[nf], ovv[mf][nf], 0, 0, 0);
        }
    }

    #pragma unroll
    for (int mf = 0; mf < 2; ++mf)
        #pragma unroll
        for (int nf = 0; nf < 4; ++nf)
            #pragma unroll
            for (int r = 0; r < 4; ++r) {
                unsigned short bv = f2bf(ovv[mf][nf][r]);
                unsigned o = __shfl_xor((unsigned)bv, 1);
                if (!(lane & 1)) {
                    int row = m0 + wv * 32 + mf * 16 + lg * 4 + r;
                    int col = h * 64 + nf * 16 + lr;
                    *reinterpret_cast<unsigned*>(q + ((size_t)b * TVn + row) * Cn + col) =
                        (unsigned)bv | (o << 16);
                }
            }
}

extern "C" void kernel_launch(void* const* d_in, const int* in_sizes, int n_in,
                              void* d_out, int out_size, void* d_ws, size_t ws_size,
                              hipStream_t stream) {
    const float* video = (const float*)d_in[0];
    const float* text  = (const float*)d_in[1];
    const float* Wq = (const float*)d_in[2];
    const float* Wk = (const float*)d_in[3];
    const float* Wv = (const float*)d_in[4];
    const float* Wo = (const float*)d_in[5];
    float* out = (float*)d_out;

    char* ws = (char*)d_ws;
    unsigned short* wq_b = (unsigned short*)(ws);                    // 2 MiB
    unsigned short* wo_b = (unsigned short*)(ws + (2u << 20));       // 2 MiB
    unsigned short* kbuf = (unsigned short*)(ws + (4u << 20));       // 616 KiB
    unsigned short* vbuf = (unsigned short*)(ws + (5u << 20));       // 616 KiB
    unsigned short* qbuf = (unsigned short*)(ws + (6u << 20));       // 64 MiB (q, then attn in-place)

    k_cvt8<<<512, 256, 0, stream>>>(Wq, wq_b, 131072);
    k_cvt8<<<512, 256, 0, stream>>>(Wo, wo_b, 131072);

    dim3 gkv(3, 8, 2);  // ceil(308/128) x 1024/128 x {K,V}
    k_gemm_kv<<<gkv, 256, 0, stream>>>(text, Wk, Wv, kbuf, vbuf, Bn * TTn);

    k_gemm_qf<<<2048, 256, 0, stream>>>(video, wq_b, qbuf);

    dim3 ga(TVn / 256, Hn, Bn);  // 32 x 16 x 4
    k_attn4<<<ga, 512, 0, stream>>>(qbuf, kbuf, vbuf);

    k_gemm_bb<0><<<2048, 256, 0, stream>>>(qbuf, wo_b, (void*)out);
}